// Round 2
// baseline (385.405 us; speedup 1.0000x reference)
//
#include <hip/hip_runtime.h>
#include <hip/hip_bf16.h>

// ModulatedConv2d (StyleGAN2): B=16, Cin=Cout=128, K=3, H=W=128, STYLE=512
// R5: 2-row output tile (128 cout x 256 px, 8 waves), ring-buffered input
//     rows (2 slots) with direct-write swizzled transpose (no scratch
//     round-trip, conflict-free 8B writes). LDS 48 KB -> 2 blocks/CU
//     (16 waves/CU). T-cost and A-staging amortized 2x per output row.

typedef __attribute__((ext_vector_type(8))) short short8;
typedef __attribute__((ext_vector_type(4))) float f32x4;

#define CONV_SCALE 0.029462782549439483f /* 1/sqrt(128*9) */
#define LIN_SCALE 0.04419417382415922f   /* 1/sqrt(512) */

__device__ __forceinline__ void async16(unsigned short* lds, const unsigned short* g) {
  __builtin_amdgcn_global_load_lds((const __attribute__((address_space(1))) void*)g,
                                   (__attribute__((address_space(3))) void*)lds, 16, 0, 0);
}

__device__ __forceinline__ unsigned int pack2bf(float a, float b) {
  unsigned short ha = __builtin_bit_cast(unsigned short, __float2bfloat16(a));
  unsigned short hb = __builtin_bit_cast(unsigned short, __float2bfloat16(b));
  return (unsigned int)ha | ((unsigned int)hb << 16);
}

// s[b][cin] = sum_d style[b,d] * mod_w[cin,d] * LIN_SCALE + mod_b[cin]
__global__ void style_kernel(const float* __restrict__ style, const float* __restrict__ mod_w,
                             const float* __restrict__ mod_b, float* __restrict__ s_ws) {
  const int gw = blockIdx.x * 4 + (threadIdx.x >> 6);  // global wave 0..2047
  const int b = gw >> 7, cin = gw & 127, lane = threadIdx.x & 63;
  const float4 s0 = *(const float4*)(style + (size_t)b * 512 + lane * 4);
  const float4 s1 = *(const float4*)(style + (size_t)b * 512 + 256 + lane * 4);
  const float4 w0 = *(const float4*)(mod_w + (size_t)cin * 512 + lane * 4);
  const float4 w1 = *(const float4*)(mod_w + (size_t)cin * 512 + 256 + lane * 4);
  float acc = s0.x * w0.x + s0.y * w0.y + s0.z * w0.z + s0.w * w0.w +
              s1.x * w1.x + s1.y * w1.y + s1.z * w1.z + s1.w * w1.w;
#pragma unroll
  for (int off = 32; off; off >>= 1) acc += __shfl_xor(acc, off);
  if (lane == 0) s_ws[b * 128 + cin] = acc * LIN_SCALE + mod_b[cin];
}

// one block per (b, cout): wmod = CONV_SCALE*weight*s ; demod = rsqrt(sum wmod^2 + 1e-8)
// write bf16 w_ws[b][ky*3+kx][cout][cin]  (cin fastest, for A-tile staging)
__global__ void modw_kernel(const float* __restrict__ weight, const float* __restrict__ s_ws,
                            unsigned short* __restrict__ w_ws) {
  const int bid = blockIdx.x;
  const int b = bid >> 7, cout = bid & 127;
  const int cin = threadIdx.x;
  const float sv = s_ws[b * 128 + cin] * CONV_SCALE;
  const float* wp = weight + ((size_t)cout * 128 + cin) * 9;
  float v[9];
  float ss = 0.f;
#pragma unroll
  for (int j = 0; j < 9; ++j) { v[j] = wp[j] * sv; ss += v[j] * v[j]; }
#pragma unroll
  for (int off = 32; off; off >>= 1) ss += __shfl_down(ss, off);
  __shared__ float red[2];
  if ((threadIdx.x & 63) == 0) red[threadIdx.x >> 6] = ss;
  __syncthreads();
  const float dem = rsqrtf(red[0] + red[1] + 1e-8f);
#pragma unroll
  for (int j = 0; j < 9; ++j) {
    __hip_bfloat16 h = __float2bfloat16(v[j] * dem);
    w_ws[(((size_t)b * 9 + j) * 128 + cout) * 128 + cin] =
        __builtin_bit_cast(unsigned short, h);
  }
}

// Transpose one input row (64 cin of this half, 128 x) fp32 NCHW -> bf16
// xr slot [x 0..127][64 cin], 16B cin-groups XOR-swizzled by (x&7), the
// 8B half-group placed at +((cq&1)*4). Thread map cq=tid&15, xq=tid>>4
// gives 16 bank-pair slots x 4 lanes per wave = conflict-free b64 writes.
__device__ __forceinline__ void transpose_row(const float* __restrict__ xb, int c0, int yy,
                                              unsigned short* __restrict__ dst, int tid) {
  const int tcq = tid & 15, txq = tid >> 4;  // cin-quad 0..15, x-quad 0..31
  if (yy < 0 || yy > 127) {
    const uint2 z = {0u, 0u};
#pragma unroll
    for (int i = 0; i < 4; ++i) {
      const int xp = txq * 4 + i;
      *(uint2*)(dst + xp * 64 + (((tcq >> 1) ^ (xp & 7)) << 3) + ((tcq & 1) << 2)) = z;
    }
    return;
  }
  const float* row = xb + (size_t)(c0 + tcq * 4) * 16384 + (size_t)yy * 128 + txq * 4;
  float4 f[4];
#pragma unroll
  for (int j = 0; j < 4; ++j) f[j] = *(const float4*)(row + (size_t)j * 16384);
#pragma unroll
  for (int i = 0; i < 4; ++i) {
    const int xp = txq * 4 + i;
    uint2 col;
    col.x = pack2bf(((const float*)&f[0])[i], ((const float*)&f[1])[i]);
    col.y = pack2bf(((const float*)&f[2])[i], ((const float*)&f[3])[i]);
    *(uint2*)(dst + xp * 64 + (((tcq >> 1) ^ (xp & 7)) << 3) + ((tcq & 1) << 2)) = col;
  }
}

// one block per (b, y-pair): out rows y0, y0+1. 8 waves (2 cout x 4 px),
// each wave 4x4 of 16x16x32 bf16 MFMA = 64 cout x 64 px of one row.
__global__ __launch_bounds__(512, 4) void conv_kernel(const float* __restrict__ x,
                                                      const unsigned short* __restrict__ wws,
                                                      float* __restrict__ out) {
  __shared__ unsigned short xr[2 * 128 * 64];  // 32 KB ring: 2 input-row slots
  __shared__ unsigned short lA[128 * 64];      // 16 KB A tile

  const int tid = threadIdx.x;
  // XCD-aware swizzle: XCD gets contiguous (b,y) range -> weight + row L2 reuse.
  const int bid = (blockIdx.x & 7) * 128 + (blockIdx.x >> 3);
  const int b = bid >> 6, y0 = (bid & 63) * 2;
  const int lane = tid & 63, w = tid >> 6;
  const int wm = w & 1, wn = w >> 1;
  const int r = wn >> 1, xh = wn & 1;  // output row in pair, x-half
  const int l15 = lane & 15, q = lane >> 4;

  f32x4 acc[4][4];
#pragma unroll
  for (int i = 0; i < 4; ++i)
#pragma unroll
    for (int t = 0; t < 4; ++t) acc[i][t] = (f32x4){0.f, 0.f, 0.f, 0.f};

  const float* xb = x + (size_t)b * (128 * 16384);
  const unsigned short* wb = wws + (size_t)b * 9 * 128 * 128;

  // A staging: 2 async16/thread, pre-swizzled global source, linear LDS dest
  const int goff = (((tid & 7) ^ ((tid >> 3) & 7)) << 3);
  const int m0 = tid >> 3;  // 0..63
  const int eoff = tid * 8;

  int nt[4];
#pragma unroll
  for (int t = 0; t < 4; ++t) nt[t] = xh * 64 + t * 16 + l15;  // x coord

  const short8 zero8 = {0, 0, 0, 0, 0, 0, 0, 0};

  for (int c0 = 0; c0 < 128; c0 += 64) {
    __syncthreads();  // xr + lA free (previous half's MFMA reads done)
    // upfront: input rows y0-1 (slot 0), y0 (slot 1)
    transpose_row(xb, c0, y0 - 1, xr, tid);
    transpose_row(xb, c0, y0, xr + 8192, tid);
    for (int ky = 0; ky < 3; ++ky) {
      for (int kx = 0; kx < 3; ++kx) {
        const int j3 = ky * 3 + kx;
        if (j3) __syncthreads();  // prev MFMA reads of lA/xr done
        async16(lA + eoff, wb + j3 * 16384 + c0 + m0 * 128 + goff);
        async16(lA + 4096 + eoff, wb + j3 * 16384 + c0 + (64 + m0) * 128 + goff);
        // slide ring: at ky>=1 bring in row y0+ky into slot (ky+1)&1
        if (kx == 0 && ky > 0)
          transpose_row(xb, c0, y0 + ky, xr + (((ky + 1) & 1) << 13), tid);
        __syncthreads();  // A staged + transpose visible
        // this wave reads input row y0 + r + ky - 1 -> slot (ky+r)&1
        const unsigned short* xkr = xr + (((ky + r) & 1) << 13);
        int xcb[4];
#pragma unroll
        for (int t = 0; t < 4; ++t) xcb[t] = nt[t] + (kx - 1);
        const bool lo = (xcb[0] < 0);
        const bool hi = (xcb[3] > 127);
        if (lo) xcb[0] = 0;
        if (hi) xcb[3] = 127;
#pragma unroll
        for (int s = 0; s < 2; ++s) {
          const int s4q = s * 4 + q;
          const int axor = ((s4q ^ (l15 & 7)) << 3);
          short8 af[4], bf[4];
#pragma unroll
          for (int i = 0; i < 4; ++i)
            af[i] = *(const short8*)(lA + (wm * 64 + i * 16 + l15) * 64 + axor);
#pragma unroll
          for (int t = 0; t < 4; ++t)
            bf[t] = *(const short8*)(xkr + xcb[t] * 64 + ((s4q ^ (xcb[t] & 7)) << 3));
          if (lo) bf[0] = zero8;
          if (hi) bf[3] = zero8;
#pragma unroll
          for (int i = 0; i < 4; ++i)
#pragma unroll
            for (int t = 0; t < 4; ++t)
              acc[i][t] = __builtin_amdgcn_mfma_f32_16x16x32_bf16(af[i], bf[t], acc[i][t], 0, 0, 0);
        }
      }
    }
  }

  // C/D layout: col(pixel) = lane&15, row(cout) = (lane>>4)*4 + reg
  float* ob = out + ((size_t)b * 128 * 128 + (y0 + r)) * 128;
#pragma unroll
  for (int i = 0; i < 4; ++i) {
    const int coutb = wm * 64 + i * 16 + q * 4;
#pragma unroll
    for (int rr = 0; rr < 4; ++rr) {
      float* orow = ob + (size_t)(coutb + rr) * (128 * 128);
#pragma unroll
      for (int t = 0; t < 4; ++t) orow[xh * 64 + t * 16 + l15] = acc[i][t][rr];
    }
  }
}

extern "C" void kernel_launch(void* const* d_in, const int* in_sizes, int n_in,
                              void* d_out, int out_size, void* d_ws, size_t ws_size,
                              hipStream_t stream) {
  const float* x = (const float*)d_in[0];
  const float* style = (const float*)d_in[1];
  const float* weight = (const float*)d_in[2];
  const float* mod_w = (const float*)d_in[3];
  const float* mod_b = (const float*)d_in[4];
  float* out = (float*)d_out;

  char* ws = (char*)d_ws;
  float* s_ws = (float*)ws;                             // 8 KB
  unsigned short* w_ws = (unsigned short*)(ws + 8192);  // 4.7 MB

  style_kernel<<<512, 256, 0, stream>>>(style, mod_w, mod_b, s_ws);
  modw_kernel<<<16 * 128, 128, 0, stream>>>(weight, s_ws, w_ws);
  conv_kernel<<<16 * 64, 512, 0, stream>>>(x, w_ws, out);
}

// Round 3
// 316.802 us; speedup vs baseline: 1.2165x; 1.2165x over previous
//
#include <hip/hip_runtime.h>
#include <hip/hip_bf16.h>

// ModulatedConv2d (StyleGAN2): B=16, Cin=Cout=128, K=3, H=W=128, STYLE=512
// R6: R5 structure (2-row output tile, 8 waves, ring-buffered transposed
//     input rows, direct-write swizzled transpose) with the launch bound
//     fixed: (512,4) was read as 4 blocks/CU -> 64-VGPR cap -> the 64-reg
//     accumulator spilled to scratch (+250 MB HBM each way). (512,2) gives
//     a 128-reg budget / 2 blocks/CU, which the live set fits.

typedef __attribute__((ext_vector_type(8))) short short8;
typedef __attribute__((ext_vector_type(4))) float f32x4;

#define CONV_SCALE 0.029462782549439483f /* 1/sqrt(128*9) */
#define LIN_SCALE 0.04419417382415922f   /* 1/sqrt(512) */

__device__ __forceinline__ void async16(unsigned short* lds, const unsigned short* g) {
  __builtin_amdgcn_global_load_lds((const __attribute__((address_space(1))) void*)g,
                                   (__attribute__((address_space(3))) void*)lds, 16, 0, 0);
}

__device__ __forceinline__ unsigned int pack2bf(float a, float b) {
  unsigned short ha = __builtin_bit_cast(unsigned short, __float2bfloat16(a));
  unsigned short hb = __builtin_bit_cast(unsigned short, __float2bfloat16(b));
  return (unsigned int)ha | ((unsigned int)hb << 16);
}

// s[b][cin] = sum_d style[b,d] * mod_w[cin,d] * LIN_SCALE + mod_b[cin]
__global__ void style_kernel(const float* __restrict__ style, const float* __restrict__ mod_w,
                             const float* __restrict__ mod_b, float* __restrict__ s_ws) {
  const int gw = blockIdx.x * 4 + (threadIdx.x >> 6);  // global wave 0..2047
  const int b = gw >> 7, cin = gw & 127, lane = threadIdx.x & 63;
  const float4 s0 = *(const float4*)(style + (size_t)b * 512 + lane * 4);
  const float4 s1 = *(const float4*)(style + (size_t)b * 512 + 256 + lane * 4);
  const float4 w0 = *(const float4*)(mod_w + (size_t)cin * 512 + lane * 4);
  const float4 w1 = *(const float4*)(mod_w + (size_t)cin * 512 + 256 + lane * 4);
  float acc = s0.x * w0.x + s0.y * w0.y + s0.z * w0.z + s0.w * w0.w +
              s1.x * w1.x + s1.y * w1.y + s1.z * w1.z + s1.w * w1.w;
#pragma unroll
  for (int off = 32; off; off >>= 1) acc += __shfl_xor(acc, off);
  if (lane == 0) s_ws[b * 128 + cin] = acc * LIN_SCALE + mod_b[cin];
}

// one block per (b, cout): wmod = CONV_SCALE*weight*s ; demod = rsqrt(sum wmod^2 + 1e-8)
// write bf16 w_ws[b][ky*3+kx][cout][cin]  (cin fastest, for A-tile staging)
__global__ void modw_kernel(const float* __restrict__ weight, const float* __restrict__ s_ws,
                            unsigned short* __restrict__ w_ws) {
  const int bid = blockIdx.x;
  const int b = bid >> 7, cout = bid & 127;
  const int cin = threadIdx.x;
  const float sv = s_ws[b * 128 + cin] * CONV_SCALE;
  const float* wp = weight + ((size_t)cout * 128 + cin) * 9;
  float v[9];
  float ss = 0.f;
#pragma unroll
  for (int j = 0; j < 9; ++j) { v[j] = wp[j] * sv; ss += v[j] * v[j]; }
#pragma unroll
  for (int off = 32; off; off >>= 1) ss += __shfl_down(ss, off);
  __shared__ float red[2];
  if ((threadIdx.x & 63) == 0) red[threadIdx.x >> 6] = ss;
  __syncthreads();
  const float dem = rsqrtf(red[0] + red[1] + 1e-8f);
#pragma unroll
  for (int j = 0; j < 9; ++j) {
    __hip_bfloat16 h = __float2bfloat16(v[j] * dem);
    w_ws[(((size_t)b * 9 + j) * 128 + cout) * 128 + cin] =
        __builtin_bit_cast(unsigned short, h);
  }
}

// Transpose one input row (64 cin of this half, 128 x) fp32 NCHW -> bf16
// xr slot [x 0..127][64 cin], 16B cin-groups XOR-swizzled by (x&7), the
// 8B half-group placed at +((cq&1)*4). Thread map cq=tid&15, xq=tid>>4
// gives 16 bank-pair slots x 4 lanes per wave = conflict-free b64 writes.
__device__ __forceinline__ void transpose_row(const float* __restrict__ xb, int c0, int yy,
                                              unsigned short* __restrict__ dst, int tid) {
  const int tcq = tid & 15, txq = tid >> 4;  // cin-quad 0..15, x-quad 0..31
  if (yy < 0 || yy > 127) {
    const uint2 z = {0u, 0u};
#pragma unroll
    for (int i = 0; i < 4; ++i) {
      const int xp = txq * 4 + i;
      *(uint2*)(dst + xp * 64 + (((tcq >> 1) ^ (xp & 7)) << 3) + ((tcq & 1) << 2)) = z;
    }
    return;
  }
  const float* row = xb + (size_t)(c0 + tcq * 4) * 16384 + (size_t)yy * 128 + txq * 4;
  float4 f[4];
#pragma unroll
  for (int j = 0; j < 4; ++j) f[j] = *(const float4*)(row + (size_t)j * 16384);
#pragma unroll
  for (int i = 0; i < 4; ++i) {
    const int xp = txq * 4 + i;
    uint2 col;
    col.x = pack2bf(((const float*)&f[0])[i], ((const float*)&f[1])[i]);
    col.y = pack2bf(((const float*)&f[2])[i], ((const float*)&f[3])[i]);
    *(uint2*)(dst + xp * 64 + (((tcq >> 1) ^ (xp & 7)) << 3) + ((tcq & 1) << 2)) = col;
  }
}

// one block per (b, y-pair): out rows y0, y0+1. 8 waves (2 cout x 4 px),
// each wave 4x4 of 16x16x32 bf16 MFMA = 64 cout x 64 px of one row.
__global__ __launch_bounds__(512, 2) void conv_kernel(const float* __restrict__ x,
                                                      const unsigned short* __restrict__ wws,
                                                      float* __restrict__ out) {
  __shared__ unsigned short xr[2 * 128 * 64];  // 32 KB ring: 2 input-row slots
  __shared__ unsigned short lA[128 * 64];      // 16 KB A tile

  const int tid = threadIdx.x;
  // XCD-aware swizzle: XCD gets contiguous (b,y) range -> weight + row L2 reuse.
  const int bid = (blockIdx.x & 7) * 128 + (blockIdx.x >> 3);
  const int b = bid >> 6, y0 = (bid & 63) * 2;
  const int lane = tid & 63, w = tid >> 6;
  const int wm = w & 1, wn = w >> 1;
  const int r = wn >> 1, xh = wn & 1;  // output row in pair, x-half
  const int l15 = lane & 15, q = lane >> 4;

  f32x4 acc[4][4];
#pragma unroll
  for (int i = 0; i < 4; ++i)
#pragma unroll
    for (int t = 0; t < 4; ++t) acc[i][t] = (f32x4){0.f, 0.f, 0.f, 0.f};

  const float* xb = x + (size_t)b * (128 * 16384);
  const unsigned short* wb = wws + (size_t)b * 9 * 128 * 128;

  // A staging: 2 async16/thread, pre-swizzled global source, linear LDS dest
  const int goff = (((tid & 7) ^ ((tid >> 3) & 7)) << 3);
  const int m0 = tid >> 3;  // 0..63
  const int eoff = tid * 8;

  int nt[4];
#pragma unroll
  for (int t = 0; t < 4; ++t) nt[t] = xh * 64 + t * 16 + l15;  // x coord

  const short8 zero8 = {0, 0, 0, 0, 0, 0, 0, 0};

  for (int c0 = 0; c0 < 128; c0 += 64) {
    __syncthreads();  // xr + lA free (previous half's MFMA reads done)
    // upfront: input rows y0-1 (slot 0), y0 (slot 1)
    transpose_row(xb, c0, y0 - 1, xr, tid);
    transpose_row(xb, c0, y0, xr + 8192, tid);
    for (int ky = 0; ky < 3; ++ky) {
      for (int kx = 0; kx < 3; ++kx) {
        const int j3 = ky * 3 + kx;
        if (j3) __syncthreads();  // prev MFMA reads of lA/xr done
        async16(lA + eoff, wb + j3 * 16384 + c0 + m0 * 128 + goff);
        async16(lA + 4096 + eoff, wb + j3 * 16384 + c0 + (64 + m0) * 128 + goff);
        // slide ring: at ky>=1 bring in row y0+ky into slot (ky+1)&1
        if (kx == 0 && ky > 0)
          transpose_row(xb, c0, y0 + ky, xr + (((ky + 1) & 1) << 13), tid);
        __syncthreads();  // A staged + transpose visible
        // this wave reads input row y0 + r + ky - 1 -> slot (ky+r)&1
        const unsigned short* xkr = xr + (((ky + r) & 1) << 13);
        int xcb[4];
#pragma unroll
        for (int t = 0; t < 4; ++t) xcb[t] = nt[t] + (kx - 1);
        const bool lo = (xcb[0] < 0);
        const bool hi = (xcb[3] > 127);
        if (lo) xcb[0] = 0;
        if (hi) xcb[3] = 127;
#pragma unroll
        for (int s = 0; s < 2; ++s) {
          const int s4q = s * 4 + q;
          const int axor = ((s4q ^ (l15 & 7)) << 3);
          short8 af[4], bf[4];
#pragma unroll
          for (int i = 0; i < 4; ++i)
            af[i] = *(const short8*)(lA + (wm * 64 + i * 16 + l15) * 64 + axor);
#pragma unroll
          for (int t = 0; t < 4; ++t)
            bf[t] = *(const short8*)(xkr + xcb[t] * 64 + ((s4q ^ (xcb[t] & 7)) << 3));
          if (lo) bf[0] = zero8;
          if (hi) bf[3] = zero8;
#pragma unroll
          for (int i = 0; i < 4; ++i)
#pragma unroll
            for (int t = 0; t < 4; ++t)
              acc[i][t] = __builtin_amdgcn_mfma_f32_16x16x32_bf16(af[i], bf[t], acc[i][t], 0, 0, 0);
        }
      }
    }
  }

  // C/D layout: col(pixel) = lane&15, row(cout) = (lane>>4)*4 + reg
  float* ob = out + ((size_t)b * 128 * 128 + (y0 + r)) * 128;
#pragma unroll
  for (int i = 0; i < 4; ++i) {
    const int coutb = wm * 64 + i * 16 + q * 4;
#pragma unroll
    for (int rr = 0; rr < 4; ++rr) {
      float* orow = ob + (size_t)(coutb + rr) * (128 * 128);
#pragma unroll
      for (int t = 0; t < 4; ++t) orow[xh * 64 + t * 16 + l15] = acc[i][t][rr];
    }
  }
}

extern "C" void kernel_launch(void* const* d_in, const int* in_sizes, int n_in,
                              void* d_out, int out_size, void* d_ws, size_t ws_size,
                              hipStream_t stream) {
  const float* x = (const float*)d_in[0];
  const float* style = (const float*)d_in[1];
  const float* weight = (const float*)d_in[2];
  const float* mod_w = (const float*)d_in[3];
  const float* mod_b = (const float*)d_in[4];
  float* out = (float*)d_out;

  char* ws = (char*)d_ws;
  float* s_ws = (float*)ws;                             // 8 KB
  unsigned short* w_ws = (unsigned short*)(ws + 8192);  // 4.7 MB

  style_kernel<<<512, 256, 0, stream>>>(style, mod_w, mod_b, s_ws);
  modw_kernel<<<16 * 128, 128, 0, stream>>>(weight, s_ws, w_ws);
  conv_kernel<<<16 * 64, 512, 0, stream>>>(x, w_ws, out);
}

// Round 4
// 307.947 us; speedup vs baseline: 1.2515x; 1.0288x over previous
//
#include <hip/hip_runtime.h>
#include <hip/hip_bf16.h>

// ModulatedConv2d (StyleGAN2): B=16, Cin=Cout=128, K=3, H=W=128, STYLE=512
// R7: fused transpose on the R3 skeleton. One output row per block,
//     256 threads / 4 waves (2x2), 3 blocks/CU. Input rows y-1,y,y+1
//     live in a 2-slot ring (32 KB) filled by the direct-write swizzled
//     transpose (conflict-free, no scratch round-trip, proven in R5/R6).
//     Per-tap staging is A-only (16 KB). LDS total 48 KB.

typedef __attribute__((ext_vector_type(8))) short short8;
typedef __attribute__((ext_vector_type(4))) float f32x4;

#define CONV_SCALE 0.029462782549439483f /* 1/sqrt(128*9) */
#define LIN_SCALE 0.04419417382415922f   /* 1/sqrt(512) */

__device__ __forceinline__ void async16(unsigned short* lds, const unsigned short* g) {
  __builtin_amdgcn_global_load_lds((const __attribute__((address_space(1))) void*)g,
                                   (__attribute__((address_space(3))) void*)lds, 16, 0, 0);
}

__device__ __forceinline__ unsigned int pack2bf(float a, float b) {
  unsigned short ha = __builtin_bit_cast(unsigned short, __float2bfloat16(a));
  unsigned short hb = __builtin_bit_cast(unsigned short, __float2bfloat16(b));
  return (unsigned int)ha | ((unsigned int)hb << 16);
}

// s[b][cin] = sum_d style[b,d] * mod_w[cin,d] * LIN_SCALE + mod_b[cin]
__global__ void style_kernel(const float* __restrict__ style, const float* __restrict__ mod_w,
                             const float* __restrict__ mod_b, float* __restrict__ s_ws) {
  const int gw = blockIdx.x * 4 + (threadIdx.x >> 6);  // global wave 0..2047
  const int b = gw >> 7, cin = gw & 127, lane = threadIdx.x & 63;
  const float4 s0 = *(const float4*)(style + (size_t)b * 512 + lane * 4);
  const float4 s1 = *(const float4*)(style + (size_t)b * 512 + 256 + lane * 4);
  const float4 w0 = *(const float4*)(mod_w + (size_t)cin * 512 + lane * 4);
  const float4 w1 = *(const float4*)(mod_w + (size_t)cin * 512 + 256 + lane * 4);
  float acc = s0.x * w0.x + s0.y * w0.y + s0.z * w0.z + s0.w * w0.w +
              s1.x * w1.x + s1.y * w1.y + s1.z * w1.z + s1.w * w1.w;
#pragma unroll
  for (int off = 32; off; off >>= 1) acc += __shfl_xor(acc, off);
  if (lane == 0) s_ws[b * 128 + cin] = acc * LIN_SCALE + mod_b[cin];
}

// one block per (b, cout): wmod = CONV_SCALE*weight*s ; demod = rsqrt(sum wmod^2 + 1e-8)
// write bf16 w_ws[b][ky*3+kx][cout][cin]  (cin fastest, for A-tile staging)
__global__ void modw_kernel(const float* __restrict__ weight, const float* __restrict__ s_ws,
                            unsigned short* __restrict__ w_ws) {
  const int bid = blockIdx.x;
  const int b = bid >> 7, cout = bid & 127;
  const int cin = threadIdx.x;
  const float sv = s_ws[b * 128 + cin] * CONV_SCALE;
  const float* wp = weight + ((size_t)cout * 128 + cin) * 9;
  float v[9];
  float ss = 0.f;
#pragma unroll
  for (int j = 0; j < 9; ++j) { v[j] = wp[j] * sv; ss += v[j] * v[j]; }
#pragma unroll
  for (int off = 32; off; off >>= 1) ss += __shfl_down(ss, off);
  __shared__ float red[2];
  if ((threadIdx.x & 63) == 0) red[threadIdx.x >> 6] = ss;
  __syncthreads();
  const float dem = rsqrtf(red[0] + red[1] + 1e-8f);
#pragma unroll
  for (int j = 0; j < 9; ++j) {
    __hip_bfloat16 h = __float2bfloat16(v[j] * dem);
    w_ws[(((size_t)b * 9 + j) * 128 + cout) * 128 + cin] =
        __builtin_bit_cast(unsigned short, h);
  }
}

// Transpose one input row (64 cin of this half, 128 x) fp32 NCHW -> bf16
// xr slot [x 0..127][64 cin], 16B cin-groups XOR-swizzled by (x&7), the
// 8B half-group placed at +((tcq&1)*4). Per-wave write pattern identical
// to R6's (measured conflict-free); 256 threads cover x-quads in 2 passes.
__device__ __forceinline__ void transpose_row(const float* __restrict__ xb, int c0, int yy,
                                              unsigned short* __restrict__ dst, int tid) {
  const int tcq = tid & 15, t4 = tid >> 4;  // cin-quad 0..15, x-quad-base 0..15
  if (yy < 0 || yy > 127) {
    const uint2 z = {0u, 0u};
#pragma unroll
    for (int xi = 0; xi < 2; ++xi)
#pragma unroll
      for (int i = 0; i < 4; ++i) {
        const int xp = (xi * 16 + t4) * 4 + i;
        *(uint2*)(dst + xp * 64 + (((tcq >> 1) ^ (xp & 7)) << 3) + ((tcq & 1) << 2)) = z;
      }
    return;
  }
  const float* row = xb + (size_t)(c0 + tcq * 4) * 16384 + (size_t)yy * 128;
#pragma unroll
  for (int xi = 0; xi < 2; ++xi) {
    const int xq = xi * 16 + t4;
    float4 f[4];
#pragma unroll
    for (int j = 0; j < 4; ++j) f[j] = *(const float4*)(row + (size_t)j * 16384 + xq * 4);
#pragma unroll
    for (int i = 0; i < 4; ++i) {
      const int xp = xq * 4 + i;
      uint2 col;
      col.x = pack2bf(((const float*)&f[0])[i], ((const float*)&f[1])[i]);
      col.y = pack2bf(((const float*)&f[2])[i], ((const float*)&f[3])[i]);
      *(uint2*)(dst + xp * 64 + (((tcq >> 1) ^ (xp & 7)) << 3) + ((tcq & 1) << 2)) = col;
    }
  }
}

// one block per (b, y): out[b][0..127][y][0..127] = sum_{ky,kx,cin} w'*x
// 128x128 tile, 4 waves 2x2, each wave 4x4 of 16x16x32 bf16 MFMA.
// Ring slots: ky -> slot (ky&1); row y+1 transposed into slot0 during
// the (ky==1,kx==0) interval (slot0's reader, ky=0, finished at the
// interval's opening barrier; ky=2 readers are behind later barriers).
__global__ __launch_bounds__(256, 3) void conv_kernel(const float* __restrict__ x,
                                                      const unsigned short* __restrict__ wws,
                                                      float* __restrict__ out) {
  __shared__ unsigned short xr[2 * 128 * 64];  // 32 KB ring: 2 input-row slots
  __shared__ unsigned short lA[128 * 64];      // 16 KB A tile

  const int tid = threadIdx.x;
  // XCD-aware swizzle: XCD gets contiguous (b,y) range -> weight + row L2 reuse.
  const int bid = (blockIdx.x & 7) * 256 + (blockIdx.x >> 3);
  const int b = bid >> 7, y = bid & 127;
  const int lane = tid & 63, w = tid >> 6;
  const int wm = w & 1, wn = w >> 1;
  const int l15 = lane & 15, q = lane >> 4;

  f32x4 acc[4][4];
#pragma unroll
  for (int i = 0; i < 4; ++i)
#pragma unroll
    for (int t = 0; t < 4; ++t) acc[i][t] = (f32x4){0.f, 0.f, 0.f, 0.f};

  const float* xb = x + (size_t)b * (128 * 16384);
  const unsigned short* wb = wws + (size_t)b * 9 * 128 * 128;

  // A staging: 4 async16/thread, pre-swizzled global source, linear LDS dest
  const int mbase = tid >> 3;  // 0..31
  const int goff = (((tid & 7) ^ ((tid >> 3) & 7)) << 3);
  const int eoff = tid * 8;

  int nt[4];
#pragma unroll
  for (int t = 0; t < 4; ++t) nt[t] = wn * 64 + t * 16 + l15;  // x coord

  const short8 zero8 = {0, 0, 0, 0, 0, 0, 0, 0};

  for (int c0 = 0; c0 < 128; c0 += 64) {
    __syncthreads();  // xr + lA free (previous half's MFMA reads done)
    transpose_row(xb, c0, y - 1, xr, tid);         // slot 0
    transpose_row(xb, c0, y, xr + 8192, tid);      // slot 1
    for (int ky = 0; ky < 3; ++ky) {
      for (int kx = 0; kx < 3; ++kx) {
        const int j3 = ky * 3 + kx;
        if (j3) __syncthreads();  // prev MFMA reads of lA/xr done
#pragma unroll
        for (int p = 0; p < 4; ++p)
          async16(lA + p * 2048 + eoff, wb + j3 * 16384 + c0 + p * 4096 + mbase * 128 + goff);
        // slide ring: row y+1 -> slot 0 (read by ky=2)
        if (ky == 1 && kx == 0) transpose_row(xb, c0, y + 1, xr, tid);
        __syncthreads();  // A staged + transpose visible
        const unsigned short* xkr = xr + ((ky & 1) << 13);
        int xcb[4];
#pragma unroll
        for (int t = 0; t < 4; ++t) xcb[t] = nt[t] + (kx - 1);
        const bool lo = (xcb[0] < 0);    // kx==0, wn==0, l15==0 lanes
        const bool hi = (xcb[3] > 127);  // kx==2, wn==1, l15==15 lanes
        if (lo) xcb[0] = 0;
        if (hi) xcb[3] = 127;
#pragma unroll
        for (int s = 0; s < 2; ++s) {
          const int s4q = s * 4 + q;
          const int axor = ((s4q ^ (l15 & 7)) << 3);
          short8 af[4], bf[4];
#pragma unroll
          for (int i = 0; i < 4; ++i)
            af[i] = *(const short8*)(lA + (wm * 64 + i * 16 + l15) * 64 + axor);
#pragma unroll
          for (int t = 0; t < 4; ++t)
            bf[t] = *(const short8*)(xkr + xcb[t] * 64 + ((s4q ^ (xcb[t] & 7)) << 3));
          if (lo) bf[0] = zero8;
          if (hi) bf[3] = zero8;
#pragma unroll
          for (int i = 0; i < 4; ++i)
#pragma unroll
            for (int t = 0; t < 4; ++t)
              acc[i][t] = __builtin_amdgcn_mfma_f32_16x16x32_bf16(af[i], bf[t], acc[i][t], 0, 0, 0);
        }
      }
    }
  }

  // C/D layout: col(pixel) = lane&15, row(cout) = (lane>>4)*4 + reg
  float* ob = out + ((size_t)b * 128 * 128 + y) * 128;
#pragma unroll
  for (int i = 0; i < 4; ++i) {
    const int coutb = wm * 64 + i * 16 + q * 4;
#pragma unroll
    for (int rr = 0; rr < 4; ++rr) {
      float* orow = ob + (size_t)(coutb + rr) * (128 * 128);
#pragma unroll
      for (int t = 0; t < 4; ++t) orow[wn * 64 + t * 16 + l15] = acc[i][t][rr];
    }
  }
}

extern "C" void kernel_launch(void* const* d_in, const int* in_sizes, int n_in,
                              void* d_out, int out_size, void* d_ws, size_t ws_size,
                              hipStream_t stream) {
  const float* x = (const float*)d_in[0];
  const float* style = (const float*)d_in[1];
  const float* weight = (const float*)d_in[2];
  const float* mod_w = (const float*)d_in[3];
  const float* mod_b = (const float*)d_in[4];
  float* out = (float*)d_out;

  char* ws = (char*)d_ws;
  float* s_ws = (float*)ws;                             // 8 KB
  unsigned short* w_ws = (unsigned short*)(ws + 8192);  // 4.7 MB

  style_kernel<<<512, 256, 0, stream>>>(style, mod_w, mod_b, s_ws);
  modw_kernel<<<16 * 128, 128, 0, stream>>>(weight, s_ws, w_ws);
  conv_kernel<<<16 * 128, 256, 0, stream>>>(x, w_ws, out);
}